// Round 1
// baseline (816.005 us; speedup 1.0000x reference)
//
#include <hip/hip_runtime.h>
#include <hip/hip_bf16.h>

#define N_NODES 50000
#define N_EDGES 800000
#define E_TOT   (N_EDGES + N_NODES)   /* 850000: edges + self-loops */
#define IN_CH   128
#define HID     64
#define HEADS   4
#define F1      256                   /* HEADS*HID */
#define OUT_CH  12
#define NEG_SLOPE 0.2f

__device__ __forceinline__ float leaky(float x) { return x > 0.f ? x : NEG_SLOPE * x; }

// ---------------- CSR build ----------------
__global__ void k_zero(int* p, int n) {
    int i = blockIdx.x * blockDim.x + threadIdx.x;
    if (i < n) p[i] = 0;
}

__global__ void k_count(const int* __restrict__ ei, int* __restrict__ counts) {
    int i = blockIdx.x * blockDim.x + threadIdx.x;
    if (i >= E_TOT) return;
    int dst = (i < N_EDGES) ? ei[N_EDGES + i] : (i - N_EDGES);
    atomicAdd(&counts[dst], 1);
}

// single-block exclusive scan over 50000 counts -> rowptr[0..N], cursor copy
__global__ void k_scan(const int* __restrict__ counts, int* __restrict__ rowptr,
                       int* __restrict__ cursor) {
    __shared__ int buf[1024];
    __shared__ int carry;
    if (threadIdx.x == 0) carry = 0;
    __syncthreads();
    for (int base = 0; base < N_NODES; base += 1024) {
        int i = base + threadIdx.x;
        int v = (i < N_NODES) ? counts[i] : 0;
        buf[threadIdx.x] = v;
        __syncthreads();
        #pragma unroll
        for (int off = 1; off < 1024; off <<= 1) {
            int t = (threadIdx.x >= off) ? buf[threadIdx.x - off] : 0;
            __syncthreads();
            buf[threadIdx.x] += t;
            __syncthreads();
        }
        int excl = buf[threadIdx.x] - v;
        int out  = carry + excl;
        if (i < N_NODES) { rowptr[i] = out; cursor[i] = out; }
        int tot = buf[1023];
        __syncthreads();
        if (threadIdx.x == 0) carry += tot;
        __syncthreads();
    }
    if (threadIdx.x == 0) rowptr[N_NODES] = carry;
}

__global__ void k_fill(const int* __restrict__ ei, int* __restrict__ cursor,
                       int* __restrict__ csr_src) {
    int i = blockIdx.x * blockDim.x + threadIdx.x;
    if (i >= E_TOT) return;
    int src, dst;
    if (i < N_EDGES) { src = ei[i]; dst = ei[N_EDGES + i]; }
    else             { src = dst = i - N_EDGES; }
    int pos = atomicAdd(&cursor[dst], 1);
    csr_src[pos] = src;
}

// ---------------- f32 tiled GEMM: C[M,N] = A[M,K] @ B[K,N] ----------------
// 64x64 tile, BK=16, 256 threads, 4x4 microtile. K must be a multiple of 16.
__global__ __launch_bounds__(256) void k_gemm(const float* __restrict__ A,
                                              const float* __restrict__ B,
                                              float* __restrict__ C,
                                              int M, int K, int N) {
    __shared__ float As[16][68];   // [k][m], padded: 68*4B row => 16B-aligned float4 reads
    __shared__ float Bs[16][64];
    const int t  = threadIdx.x;
    const int tx = t & 15, ty = t >> 4;
    const int row0 = blockIdx.y * 64, col0 = blockIdx.x * 64;

    const int am = t >> 2;         // 0..63 row within tile
    const int ak = (t & 3) * 4;    // 0,4,8,12
    const int bk = t >> 4;         // 0..15
    const int bn = (t & 15) * 4;   // 0..60

    float acc[4][4] = {};
    for (int k0 = 0; k0 < K; k0 += 16) {
        float4 av = make_float4(0.f, 0.f, 0.f, 0.f);
        int ar = row0 + am;
        if (ar < M) av = *(const float4*)&A[(size_t)ar * K + k0 + ak];
        As[ak + 0][am] = av.x; As[ak + 1][am] = av.y;
        As[ak + 2][am] = av.z; As[ak + 3][am] = av.w;
        float4 bv = *(const float4*)&B[(size_t)(k0 + bk) * N + col0 + bn];
        *(float4*)&Bs[bk][bn] = bv;
        __syncthreads();
        #pragma unroll
        for (int kk = 0; kk < 16; ++kk) {
            const float4 a4 = *(const float4*)&As[kk][ty * 4];
            const float4 b4 = *(const float4*)&Bs[kk][tx * 4];
            const float a[4] = { a4.x, a4.y, a4.z, a4.w };
            const float b[4] = { b4.x, b4.y, b4.z, b4.w };
            #pragma unroll
            for (int i = 0; i < 4; ++i)
                #pragma unroll
                for (int j = 0; j < 4; ++j)
                    acc[i][j] = fmaf(a[i], b[j], acc[i][j]);
        }
        __syncthreads();
    }
    #pragma unroll
    for (int i = 0; i < 4; ++i) {
        int r = row0 + ty * 4 + i;
        if (r < M)
            *(float4*)&C[(size_t)r * N + col0 + tx * 4] =
                make_float4(acc[i][0], acc[i][1], acc[i][2], acc[i][3]);
    }
}

// ---------------- attention coefficients: alpha_s/d[n,h] = <h[n,h,:], att[h,:]> ----------------
__global__ __launch_bounds__(256) void k_attn(const float* __restrict__ H,
                                              const float* __restrict__ a_src,
                                              const float* __restrict__ a_dst,
                                              float* __restrict__ oS,
                                              float* __restrict__ oD) {
    int lane = threadIdx.x & 63, wid = threadIdx.x >> 6;
    int node = blockIdx.x * 4 + wid;
    int head = lane >> 4, cc = (lane & 15) * 4;
    float4 hv = *(const float4*)&H[(size_t)node * F1 + lane * 4];
    float4 sv = *(const float4*)&a_src[head * HID + cc];
    float4 dv = *(const float4*)&a_dst[head * HID + cc];
    float s = hv.x * sv.x + hv.y * sv.y + hv.z * sv.z + hv.w * sv.w;
    float d = hv.x * dv.x + hv.y * dv.y + hv.z * dv.z + hv.w * dv.w;
    #pragma unroll
    for (int off = 1; off < 16; off <<= 1) {
        s += __shfl_xor(s, off);
        d += __shfl_xor(d, off);
    }
    if ((lane & 15) == 0) { oS[node * 4 + head] = s; oD[node * 4 + head] = d; }
}

// ---------------- per-destination-node softmax + aggregate (one wave per node) ----------------
__global__ __launch_bounds__(256) void k_agg(const float* __restrict__ H,
                                             const float* __restrict__ aS,
                                             const float* __restrict__ aD,
                                             const int* __restrict__ rowptr,
                                             const int* __restrict__ csr,
                                             const float* __restrict__ bias,
                                             float* __restrict__ O) {
    int lane = threadIdx.x & 63, wid = threadIdx.x >> 6;
    int node = blockIdx.x * 4 + wid;
    int beg = rowptr[node], end = rowptr[node + 1];

    float4 adv = *(const float4*)&aD[node * 4];
    float ad[4] = { adv.x, adv.y, adv.z, adv.w };
    float m[4] = { -1e30f, -1e30f, -1e30f, -1e30f };
    float s[4] = { 0.f, 0.f, 0.f, 0.f };

    for (int j = beg + lane; j < end; j += 64) {
        int src = csr[j];
        float4 asv = *(const float4*)&aS[src * 4];
        float as4[4] = { asv.x, asv.y, asv.z, asv.w };
        #pragma unroll
        for (int h = 0; h < 4; ++h) {
            float e  = leaky(as4[h] + ad[h]);
            float mn = fmaxf(m[h], e);
            s[h] = s[h] * __expf(m[h] - mn) + __expf(e - mn);
            m[h] = mn;
        }
    }
    #pragma unroll
    for (int off = 1; off < 64; off <<= 1) {
        #pragma unroll
        for (int h = 0; h < 4; ++h) {
            float mo = __shfl_xor(m[h], off);
            float so = __shfl_xor(s[h], off);
            float mn = fmaxf(m[h], mo);
            s[h] = s[h] * __expf(m[h] - mn) + so * __expf(mo - mn);
            m[h] = mn;
        }
    }
    int   hl  = lane >> 4;
    float mh  = m[hl];
    float inv = 1.f / (s[hl] + 1e-16f);
    float adh = ad[hl];
    float4 acc = make_float4(0.f, 0.f, 0.f, 0.f);
    for (int j = beg; j < end; ++j) {
        int src = csr[j];
        float e = leaky(aS[src * 4 + hl] + adh);
        float w = __expf(e - mh) * inv;
        float4 hv = *(const float4*)&H[(size_t)src * F1 + lane * 4];
        acc.x += w * hv.x; acc.y += w * hv.y; acc.z += w * hv.z; acc.w += w * hv.w;
    }
    float4 bv = *(const float4*)&bias[lane * 4];
    float4 o;
    o.x = fmaxf(acc.x + bv.x, 0.f);
    o.y = fmaxf(acc.y + bv.y, 0.f);
    o.z = fmaxf(acc.z + bv.z, 0.f);
    o.w = fmaxf(acc.w + bv.w, 0.f);
    *(float4*)&O[(size_t)node * F1 + lane * 4] = o;
}

// ---------------- Conv1d over node axis as GEMM: Y[M,64] = A[M,768] @ B[768,64] ----------------
// A[n, k*256+c] = H[n+k-1, c] (zero-padded), B[k*256+c, o] = CW[o, c, k]
__global__ __launch_bounds__(256) void k_conv(const float* __restrict__ H,
                                              const float* __restrict__ CW,
                                              const float* __restrict__ CB,
                                              float* __restrict__ Y) {
    __shared__ float As[16][68];
    __shared__ float Bs[16][64];
    const int t  = threadIdx.x;
    const int tx = t & 15, ty = t >> 4;
    const int row0 = blockIdx.x * 64;

    const int am  = t >> 2;
    const int akq = (t & 3) * 4;
    const int bkk = t >> 4;
    const int bo4 = (t & 15) * 4;

    float acc[4][4] = {};
    for (int k0 = 0; k0 < 768; k0 += 16) {
        // A gather (float4 stays within one k-segment since akq%4==0)
        int kkc  = k0 + akq;
        int kseg = kkc >> 8;
        int c    = kkc & 255;
        int r    = row0 + am + kseg - 1;
        float4 av = make_float4(0.f, 0.f, 0.f, 0.f);
        if (r >= 0 && r < N_NODES) av = *(const float4*)&H[(size_t)r * F1 + c];
        As[akq + 0][am] = av.x; As[akq + 1][am] = av.y;
        As[akq + 2][am] = av.z; As[akq + 3][am] = av.w;
        // B gather
        int kk2 = k0 + bkk, k2 = kk2 >> 8, c2 = kk2 & 255;
        #pragma unroll
        for (int j = 0; j < 4; ++j)
            Bs[bkk][bo4 + j] = CW[(size_t)(bo4 + j) * 768 + c2 * 3 + k2];
        __syncthreads();
        #pragma unroll
        for (int kk = 0; kk < 16; ++kk) {
            const float4 a4 = *(const float4*)&As[kk][ty * 4];
            const float4 b4 = *(const float4*)&Bs[kk][tx * 4];
            const float a[4] = { a4.x, a4.y, a4.z, a4.w };
            const float b[4] = { b4.x, b4.y, b4.z, b4.w };
            #pragma unroll
            for (int i = 0; i < 4; ++i)
                #pragma unroll
                for (int j = 0; j < 4; ++j)
                    acc[i][j] = fmaf(a[i], b[j], acc[i][j]);
        }
        __syncthreads();
    }
    #pragma unroll
    for (int i = 0; i < 4; ++i) {
        int r = row0 + ty * 4 + i;
        if (r < N_NODES) {
            float4 o;
            o.x = fmaxf(acc[i][0] + CB[tx * 4 + 0], 0.f);
            o.y = fmaxf(acc[i][1] + CB[tx * 4 + 1], 0.f);
            o.z = fmaxf(acc[i][2] + CB[tx * 4 + 2], 0.f);
            o.w = fmaxf(acc[i][3] + CB[tx * 4 + 3], 0.f);
            *(float4*)&Y[(size_t)r * HID + tx * 4] = o;
        }
    }
}

// ---------------- final linear: OUT[n,12] = Y[n,:64] @ LW[64,12] + LB ----------------
__global__ __launch_bounds__(256) void k_lin(const float* __restrict__ Y,
                                             const float* __restrict__ LW,
                                             const float* __restrict__ LB,
                                             float* __restrict__ OUT) {
    __shared__ float w[64][12];
    __shared__ float b[12];
    for (int i = threadIdx.x; i < 64 * 12; i += 256) w[i / 12][i % 12] = LW[i];
    if (threadIdx.x < 12) b[threadIdx.x] = LB[threadIdx.x];
    __syncthreads();
    int n = blockIdx.x * 256 + threadIdx.x;
    if (n >= N_NODES) return;
    float acc[12];
    #pragma unroll
    for (int o = 0; o < 12; ++o) acc[o] = b[o];
    for (int c = 0; c < 64; c += 4) {
        float4 yv = *(const float4*)&Y[(size_t)n * HID + c];
        #pragma unroll
        for (int o = 0; o < 12; ++o)
            acc[o] += yv.x * w[c][o] + yv.y * w[c + 1][o]
                    + yv.z * w[c + 2][o] + yv.w * w[c + 3][o];
    }
    #pragma unroll
    for (int o = 0; o < 12; ++o) OUT[(size_t)n * OUT_CH + o] = acc[o];
}

extern "C" void kernel_launch(void* const* d_in, const int* in_sizes, int n_in,
                              void* d_out, int out_size, void* d_ws, size_t ws_size,
                              hipStream_t stream) {
    const float* x   = (const float*)d_in[0];
    const int*   ei  = (const int*)d_in[1];
    const float* W1  = (const float*)d_in[2];
    const float* as1 = (const float*)d_in[3];
    const float* ad1 = (const float*)d_in[4];
    const float* b1  = (const float*)d_in[5];
    const float* W2  = (const float*)d_in[6];
    const float* as2 = (const float*)d_in[7];
    const float* ad2 = (const float*)d_in[8];
    const float* b2  = (const float*)d_in[9];
    const float* cw  = (const float*)d_in[10];
    const float* cb  = (const float*)d_in[11];
    const float* lw  = (const float*)d_in[12];
    const float* lb  = (const float*)d_in[13];
    float* out = (float*)d_out;

    char* ws = (char*)d_ws;
    size_t off = 0;
    auto alloc = [&](size_t bytes) -> void* {
        off = (off + 255) & ~(size_t)255;
        void* p = ws + off;
        off += bytes;
        return p;
    };
    float* bufA   = (float*)alloc((size_t)N_NODES * F1 * 4);  // linear-transform output h
    float* bufB   = (float*)alloc((size_t)N_NODES * F1 * 4);  // aggregated layer output
    float* alS    = (float*)alloc((size_t)N_NODES * 4 * 4);
    float* alD    = (float*)alloc((size_t)N_NODES * 4 * 4);
    int*   counts = (int*)  alloc((size_t)N_NODES * 4);
    int*   rowptr = (int*)  alloc((size_t)(N_NODES + 1) * 4);
    int*   cursor = (int*)  alloc((size_t)N_NODES * 4);
    int*   csr    = (int*)  alloc((size_t)E_TOT * 4);
    float* y      = (float*)alloc((size_t)N_NODES * HID * 4);

    // CSR build (graph identical for both layers)
    k_zero <<<(N_NODES + 255) / 256, 256, 0, stream>>>(counts, N_NODES);
    k_count<<<(E_TOT + 255) / 256, 256, 0, stream>>>(ei, counts);
    k_scan <<<1, 1024, 0, stream>>>(counts, rowptr, cursor);
    k_fill <<<(E_TOT + 255) / 256, 256, 0, stream>>>(ei, cursor, csr);

    dim3 gg(F1 / 64, (N_NODES + 63) / 64);
    // layer 1
    k_gemm<<<gg, 256, 0, stream>>>(x, W1, bufA, N_NODES, IN_CH, F1);
    k_attn<<<N_NODES / 4, 256, 0, stream>>>(bufA, as1, ad1, alS, alD);
    k_agg <<<N_NODES / 4, 256, 0, stream>>>(bufA, alS, alD, rowptr, csr, b1, bufB);
    // layer 2
    k_gemm<<<gg, 256, 0, stream>>>(bufB, W2, bufA, N_NODES, F1, F1);
    k_attn<<<N_NODES / 4, 256, 0, stream>>>(bufA, as2, ad2, alS, alD);
    k_agg <<<N_NODES / 4, 256, 0, stream>>>(bufA, alS, alD, rowptr, csr, b2, bufB);
    // conv1d over node axis + final linear
    k_conv<<<(N_NODES + 63) / 64, 256, 0, stream>>>(bufB, cw, cb, y);
    k_lin <<<(N_NODES + 255) / 256, 256, 0, stream>>>(y, lw, lb, out);
}

// Round 10
// 575.698 us; speedup vs baseline: 1.4174x; 1.4174x over previous
//
#include <hip/hip_runtime.h>
#include <hip/hip_bf16.h>

#define N_NODES 50000
#define N_EDGES 800000
#define E_TOT   (N_EDGES + N_NODES)   /* 850000: edges + self-loops */
#define IN_CH   128
#define HID     64
#define HEADS   4
#define F1      256                   /* HEADS*HID */
#define OUT_CH  12
#define NEG_SLOPE 0.2f

typedef __attribute__((ext_vector_type(8))) short  bf16x8;
typedef __attribute__((ext_vector_type(4))) float  f32x4;

__device__ __forceinline__ float leaky(float x) { return x > 0.f ? x : NEG_SLOPE * x; }

// f32 -> bf16 round-to-nearest-even
__device__ __forceinline__ unsigned short tob(float f) {
    unsigned u = __float_as_uint(f);
    u += 0x7fffu + ((u >> 16) & 1u);
    return (unsigned short)(u >> 16);
}
__device__ __forceinline__ float fromb(unsigned short s) {
    return __uint_as_float(((unsigned)s) << 16);
}

// ---------------- CSR build ----------------
__global__ void k_zero(int* p, int n) {
    int i = blockIdx.x * blockDim.x + threadIdx.x;
    if (i < n) p[i] = 0;
}

__global__ void k_count(const int* __restrict__ ei, int* __restrict__ counts) {
    int i = blockIdx.x * blockDim.x + threadIdx.x;
    if (i >= E_TOT) return;
    int dst = (i < N_EDGES) ? ei[N_EDGES + i] : (i - N_EDGES);
    atomicAdd(&counts[dst], 1);
}

// single-block exclusive scan, shuffle-based
__global__ __launch_bounds__(1024) void k_scan(const int* __restrict__ counts,
                                               int* __restrict__ rowptr,
                                               int* __restrict__ cursor) {
    __shared__ int wsum[16];
    __shared__ int carrysh;
    const int lane = threadIdx.x & 63, w = threadIdx.x >> 6;
    if (threadIdx.x == 0) carrysh = 0;
    __syncthreads();
    for (int base = 0; base < N_NODES; base += 1024) {
        int i = base + threadIdx.x;
        int v = (i < N_NODES) ? counts[i] : 0;
        int s = v;
        #pragma unroll
        for (int off = 1; off < 64; off <<= 1) {
            int t = __shfl_up(s, off);
            if (lane >= off) s += t;
        }
        if (lane == 63) wsum[w] = s;
        __syncthreads();
        int woff = 0;
        for (int j = 0; j < w; ++j) woff += wsum[j];
        int incl = carrysh + woff + s;
        if (i < N_NODES) { rowptr[i] = incl - v; cursor[i] = incl - v; }
        __syncthreads();
        if (threadIdx.x == 1023) carrysh = incl;
        __syncthreads();
    }
    if (threadIdx.x == 0) rowptr[N_NODES] = carrysh;
}

__global__ void k_fill(const int* __restrict__ ei, int* __restrict__ cursor,
                       int* __restrict__ csr_src) {
    int i = blockIdx.x * blockDim.x + threadIdx.x;
    if (i >= E_TOT) return;
    int src, dst;
    if (i < N_EDGES) { src = ei[i]; dst = ei[N_EDGES + i]; }
    else             { src = dst = i - N_EDGES; }
    int pos = atomicAdd(&cursor[dst], 1);
    csr_src[pos] = src;
}

// ---------------- casts / weight prep ----------------
__global__ void k_cast4(const float* __restrict__ in, unsigned short* __restrict__ out, int n4) {
    int i = blockIdx.x * blockDim.x + threadIdx.x;
    if (i >= n4) return;
    float4 v = *(const float4*)&in[i * 4];
    ushort4 o;
    o.x = tob(v.x); o.y = tob(v.y); o.z = tob(v.z); o.w = tob(v.w);
    *(ushort4*)&out[i * 4] = o;
}

// WT[n*K+k] = bf16(W[k*N+n]); W is K x N row-major
__global__ void k_prep_wt(const float* __restrict__ W, unsigned short* __restrict__ WT,
                          int K, int N) {
    int idx = blockIdx.x * blockDim.x + threadIdx.x;
    if (idx >= K * N) return;
    int n = idx / K, k = idx % K;
    WT[idx] = tob(W[(size_t)k * N + n]);
}

// conv weights CW[o][c][k] (64 x 256 x 3) -> BT[o][kseg*256+c]  (64 x 768)
__global__ void k_prep_cw(const float* __restrict__ CW, unsigned short* __restrict__ BT) {
    int idx = blockIdx.x * blockDim.x + threadIdx.x;
    if (idx >= 64 * 768) return;
    int o = idx / 768, kk = idx % 768;
    int kseg = kk >> 8, c = kk & 255;
    BT[idx] = tob(CW[((size_t)o * 256 + c) * 3 + kseg]);
}

// ---------------- bf16 MFMA GEMM: C[M,F1] = A[M,K] @ BT[F1,K]^T ----------------
// 128x128 tile, BK=32, 4 waves (2x2), each wave 64x64 via 4x4 frags of 16x16x32.
// Staging: 256 threads x 16 shorts = 4096 = full 128x32 tile.
__global__ __launch_bounds__(256) void k_gemm_bf16(const unsigned short* __restrict__ A,
                                                   const unsigned short* __restrict__ BT,
                                                   unsigned short* __restrict__ C,
                                                   int M, int K) {
    __shared__ unsigned short As[128][40];   // 40 = 32 + 8 pad (row stride 80 B)
    __shared__ unsigned short Bs[128][40];
    const int t    = threadIdx.x;
    const int lane = t & 63, wave = t >> 6;
    const int wr = wave >> 1, wc = wave & 1;
    const int row0 = blockIdx.y * 128, col0 = blockIdx.x * 128;
    const int r = t & 127, half = t >> 7;
    const int l15 = lane & 15, kg = lane >> 4;

    f32x4 acc[4][4];
    #pragma unroll
    for (int m = 0; m < 4; ++m)
        #pragma unroll
        for (int n = 0; n < 4; ++n) acc[m][n] = 0.f;

    for (int k0 = 0; k0 < K; k0 += 32) {
        int ar = row0 + r;
        uint4 av0 = make_uint4(0, 0, 0, 0), av1 = make_uint4(0, 0, 0, 0);
        if (ar < M) {
            const unsigned short* ap = &A[(size_t)ar * K + k0 + half * 16];
            av0 = *(const uint4*)ap;
            av1 = *(const uint4*)(ap + 8);
        }
        *(uint4*)&As[r][half * 16]     = av0;
        *(uint4*)&As[r][half * 16 + 8] = av1;
        const unsigned short* bp = &BT[(size_t)(col0 + r) * K + k0 + half * 16];
        uint4 bv0 = *(const uint4*)bp;
        uint4 bv1 = *(const uint4*)(bp + 8);
        *(uint4*)&Bs[r][half * 16]     = bv0;
        *(uint4*)&Bs[r][half * 16 + 8] = bv1;
        __syncthreads();
        bf16x8 af[4], bf[4];
        #pragma unroll
        for (int m = 0; m < 4; ++m) af[m] = *(const bf16x8*)&As[wr * 64 + m * 16 + l15][kg * 8];
        #pragma unroll
        for (int n = 0; n < 4; ++n) bf[n] = *(const bf16x8*)&Bs[wc * 64 + n * 16 + l15][kg * 8];
        #pragma unroll
        for (int m = 0; m < 4; ++m)
            #pragma unroll
            for (int n = 0; n < 4; ++n)
                acc[m][n] = __builtin_amdgcn_mfma_f32_16x16x32_bf16(af[m], bf[n], acc[m][n], 0, 0, 0);
        __syncthreads();
    }
    #pragma unroll
    for (int m = 0; m < 4; ++m) {
        #pragma unroll
        for (int j = 0; j < 4; ++j) {
            int row = row0 + wr * 64 + m * 16 + (lane >> 4) * 4 + j;
            if (row < M) {
                #pragma unroll
                for (int n = 0; n < 4; ++n)
                    C[(size_t)row * F1 + col0 + wc * 64 + n * 16 + l15] = tob(acc[m][n][j]);
            }
        }
    }
}

// ---------------- attention coefficients from bf16 h ----------------
__global__ __launch_bounds__(256) void k_attn(const unsigned short* __restrict__ H,
                                              const float* __restrict__ a_src,
                                              const float* __restrict__ a_dst,
                                              float* __restrict__ oS,
                                              float* __restrict__ oD) {
    int lane = threadIdx.x & 63, wid = threadIdx.x >> 6;
    int node = blockIdx.x * 4 + wid;
    int head = lane >> 4, cc = (lane & 15) * 4;
    ushort4 hv4 = *(const ushort4*)&H[(size_t)node * F1 + lane * 4];
    float h0 = fromb(hv4.x), h1 = fromb(hv4.y), h2 = fromb(hv4.z), h3 = fromb(hv4.w);
    float4 sv = *(const float4*)&a_src[head * HID + cc];
    float4 dv = *(const float4*)&a_dst[head * HID + cc];
    float s = h0 * sv.x + h1 * sv.y + h2 * sv.z + h3 * sv.w;
    float d = h0 * dv.x + h1 * dv.y + h2 * dv.z + h3 * dv.w;
    #pragma unroll
    for (int off = 1; off < 16; off <<= 1) {
        s += __shfl_xor(s, off);
        d += __shfl_xor(d, off);
    }
    if ((lane & 15) == 0) { oS[node * 4 + head] = s; oD[node * 4 + head] = d; }
}

// ---------------- per-destination softmax + aggregate (one wave per node), bf16 gather ----------------
__global__ __launch_bounds__(256) void k_agg(const unsigned short* __restrict__ H,
                                             const float* __restrict__ aS,
                                             const float* __restrict__ aD,
                                             const int* __restrict__ rowptr,
                                             const int* __restrict__ csr,
                                             const float* __restrict__ bias,
                                             unsigned short* __restrict__ O) {
    int lane = threadIdx.x & 63, wid = threadIdx.x >> 6;
    int node = blockIdx.x * 4 + wid;
    int beg = rowptr[node], end = rowptr[node + 1];

    float4 adv = *(const float4*)&aD[node * 4];
    float ad[4] = { adv.x, adv.y, adv.z, adv.w };
    float m[4] = { -1e30f, -1e30f, -1e30f, -1e30f };
    float s[4] = { 0.f, 0.f, 0.f, 0.f };

    for (int j = beg + lane; j < end; j += 64) {
        int src = csr[j];
        float4 asv = *(const float4*)&aS[src * 4];
        float as4[4] = { asv.x, asv.y, asv.z, asv.w };
        #pragma unroll
        for (int h = 0; h < 4; ++h) {
            float e  = leaky(as4[h] + ad[h]);
            float mn = fmaxf(m[h], e);
            s[h] = s[h] * __expf(m[h] - mn) + __expf(e - mn);
            m[h] = mn;
        }
    }
    #pragma unroll
    for (int off = 1; off < 64; off <<= 1) {
        #pragma unroll
        for (int h = 0; h < 4; ++h) {
            float mo = __shfl_xor(m[h], off);
            float so = __shfl_xor(s[h], off);
            float mn = fmaxf(m[h], mo);
            s[h] = s[h] * __expf(m[h] - mn) + so * __expf(mo - mn);
            m[h] = mn;
        }
    }
    int   hl  = lane >> 4;
    float mh  = m[hl];
    float inv = 1.f / (s[hl] + 1e-16f);
    float adh = ad[hl];
    float a0 = 0.f, a1 = 0.f, a2 = 0.f, a3 = 0.f;
    for (int j = beg; j < end; ++j) {
        int src = csr[j];
        float e = leaky(aS[src * 4 + hl] + adh);
        float w = __expf(e - mh) * inv;
        ushort4 hv = *(const ushort4*)&H[(size_t)src * F1 + lane * 4];
        a0 += w * fromb(hv.x); a1 += w * fromb(hv.y);
        a2 += w * fromb(hv.z); a3 += w * fromb(hv.w);
    }
    float4 bv = *(const float4*)&bias[lane * 4];
    ushort4 o;
    o.x = tob(fmaxf(a0 + bv.x, 0.f));
    o.y = tob(fmaxf(a1 + bv.y, 0.f));
    o.z = tob(fmaxf(a2 + bv.z, 0.f));
    o.w = tob(fmaxf(a3 + bv.w, 0.f));
    *(ushort4*)&O[(size_t)node * F1 + lane * 4] = o;
}

// ---------------- Conv1d as MFMA GEMM: Y[M,64] = A[M,768] @ BcT[64,768]^T ----------------
// A[n, kseg*256+c] = H[n+kseg-1, c] (zero-padded rows)
__global__ __launch_bounds__(256) void k_conv(const unsigned short* __restrict__ H,
                                              const unsigned short* __restrict__ BcT,
                                              const float* __restrict__ CB,
                                              float* __restrict__ Y) {
    __shared__ unsigned short As[128][40];
    __shared__ unsigned short Bs[64][40];
    const int t    = threadIdx.x;
    const int lane = t & 63, wave = t >> 6;     // wave = wr (4x1), wc = 0
    const int row0 = blockIdx.x * 128;
    const int r = t & 127, half = t >> 7;
    const int l15 = lane & 15, kg = lane >> 4;

    f32x4 acc[2][4];
    #pragma unroll
    for (int m = 0; m < 2; ++m)
        #pragma unroll
        for (int n = 0; n < 4; ++n) acc[m][n] = 0.f;

    for (int k0 = 0; k0 < 768; k0 += 32) {
        int kseg = k0 >> 8;
        int cbase = (k0 & 255) + half * 16;
        int gr = row0 + r + kseg - 1;
        uint4 av0 = make_uint4(0, 0, 0, 0), av1 = make_uint4(0, 0, 0, 0);
        if (gr >= 0 && gr < N_NODES) {
            const unsigned short* hp = &H[(size_t)gr * F1 + cbase];
            av0 = *(const uint4*)hp;
            av1 = *(const uint4*)(hp + 8);
        }
        *(uint4*)&As[r][half * 16]     = av0;
        *(uint4*)&As[r][half * 16 + 8] = av1;
        if (t < 128) {
            int br = t & 63, bh = t >> 6;
            const unsigned short* bp = &BcT[(size_t)br * 768 + k0 + bh * 16];
            uint4 bv0 = *(const uint4*)bp;
            uint4 bv1 = *(const uint4*)(bp + 8);
            *(uint4*)&Bs[br][bh * 16]     = bv0;
            *(uint4*)&Bs[br][bh * 16 + 8] = bv1;
        }
        __syncthreads();
        bf16x8 af[2], bf[4];
        #pragma unroll
        for (int m = 0; m < 2; ++m) af[m] = *(const bf16x8*)&As[wave * 32 + m * 16 + l15][kg * 8];
        #pragma unroll
        for (int n = 0; n < 4; ++n) bf[n] = *(const bf16x8*)&Bs[n * 16 + l15][kg * 8];
        #pragma unroll
        for (int m = 0; m < 2; ++m)
            #pragma unroll
            for (int n = 0; n < 4; ++n)
                acc[m][n] = __builtin_amdgcn_mfma_f32_16x16x32_bf16(af[m], bf[n], acc[m][n], 0, 0, 0);
        __syncthreads();
    }
    #pragma unroll
    for (int m = 0; m < 2; ++m) {
        #pragma unroll
        for (int j = 0; j < 4; ++j) {
            int row = row0 + wave * 32 + m * 16 + (lane >> 4) * 4 + j;
            if (row < N_NODES) {
                #pragma unroll
                for (int n = 0; n < 4; ++n) {
                    int col = n * 16 + l15;
                    Y[(size_t)row * HID + col] = fmaxf(acc[m][n][j] + CB[col], 0.f);
                }
            }
        }
    }
}

// ---------------- final linear ----------------
__global__ __launch_bounds__(256) void k_lin(const float* __restrict__ Y,
                                             const float* __restrict__ LW,
                                             const float* __restrict__ LB,
                                             float* __restrict__ OUT) {
    __shared__ float w[64][12];
    __shared__ float b[12];
    for (int i = threadIdx.x; i < 64 * 12; i += 256) w[i / 12][i % 12] = LW[i];
    if (threadIdx.x < 12) b[threadIdx.x] = LB[threadIdx.x];
    __syncthreads();
    int n = blockIdx.x * 256 + threadIdx.x;
    if (n >= N_NODES) return;
    float acc[12];
    #pragma unroll
    for (int o = 0; o < 12; ++o) acc[o] = b[o];
    for (int c = 0; c < 64; c += 4) {
        float4 yv = *(const float4*)&Y[(size_t)n * HID + c];
        #pragma unroll
        for (int o = 0; o < 12; ++o)
            acc[o] += yv.x * w[c][o] + yv.y * w[c + 1][o]
                    + yv.z * w[c + 2][o] + yv.w * w[c + 3][o];
    }
    #pragma unroll
    for (int o = 0; o < 12; ++o) OUT[(size_t)n * OUT_CH + o] = acc[o];
}

extern "C" void kernel_launch(void* const* d_in, const int* in_sizes, int n_in,
                              void* d_out, int out_size, void* d_ws, size_t ws_size,
                              hipStream_t stream) {
    const float* x   = (const float*)d_in[0];
    const int*   ei  = (const int*)d_in[1];
    const float* W1  = (const float*)d_in[2];
    const float* as1 = (const float*)d_in[3];
    const float* ad1 = (const float*)d_in[4];
    const float* b1  = (const float*)d_in[5];
    const float* W2  = (const float*)d_in[6];
    const float* as2 = (const float*)d_in[7];
    const float* ad2 = (const float*)d_in[8];
    const float* b2  = (const float*)d_in[9];
    const float* cw  = (const float*)d_in[10];
    const float* cb  = (const float*)d_in[11];
    const float* lw  = (const float*)d_in[12];
    const float* lb  = (const float*)d_in[13];
    float* out = (float*)d_out;

    char* ws = (char*)d_ws;
    size_t off = 0;
    auto alloc = [&](size_t bytes) -> void* {
        off = (off + 255) & ~(size_t)255;
        void* p = ws + off;
        off += bytes;
        return p;
    };
    unsigned short* hA  = (unsigned short*)alloc((size_t)N_NODES * F1 * 2);  // gemm out (h)
    unsigned short* hB  = (unsigned short*)alloc((size_t)N_NODES * F1 * 2);  // agg out
    unsigned short* xb  = (unsigned short*)alloc((size_t)N_NODES * IN_CH * 2);
    unsigned short* wt1 = (unsigned short*)alloc((size_t)F1 * IN_CH * 2);
    unsigned short* wt2 = (unsigned short*)alloc((size_t)F1 * F1 * 2);
    unsigned short* cwt = (unsigned short*)alloc((size_t)HID * 768 * 2);
    float* alS    = (float*)alloc((size_t)N_NODES * 4 * 4);
    float* alD    = (float*)alloc((size_t)N_NODES * 4 * 4);
    int*   counts = (int*)  alloc((size_t)N_NODES * 4);
    int*   rowptr = (int*)  alloc((size_t)(N_NODES + 1) * 4);
    int*   cursor = (int*)  alloc((size_t)N_NODES * 4);
    int*   csr    = (int*)  alloc((size_t)E_TOT * 4);
    float* y      = (float*)alloc((size_t)N_NODES * HID * 4);

    // CSR build
    k_zero <<<(N_NODES + 255) / 256, 256, 0, stream>>>(counts, N_NODES);
    k_count<<<(E_TOT + 255) / 256, 256, 0, stream>>>(ei, counts);
    k_scan <<<1, 1024, 0, stream>>>(counts, rowptr, cursor);
    k_fill <<<(E_TOT + 255) / 256, 256, 0, stream>>>(ei, cursor, csr);

    // casts / weight prep
    k_cast4 <<<(N_NODES * IN_CH / 4 + 255) / 256, 256, 0, stream>>>(x, xb, N_NODES * IN_CH / 4);
    k_prep_wt<<<(IN_CH * F1 + 255) / 256, 256, 0, stream>>>(W1, wt1, IN_CH, F1);
    k_prep_wt<<<(F1 * F1 + 255) / 256, 256, 0, stream>>>(W2, wt2, F1, F1);
    k_prep_cw<<<(HID * 768 + 255) / 256, 256, 0, stream>>>(cw, cwt);

    dim3 gg(F1 / 128, (N_NODES + 127) / 128);
    // layer 1
    k_gemm_bf16<<<gg, 256, 0, stream>>>(xb, wt1, hA, N_NODES, IN_CH);
    k_attn<<<N_NODES / 4, 256, 0, stream>>>(hA, as1, ad1, alS, alD);
    k_agg <<<N_NODES / 4, 256, 0, stream>>>(hA, alS, alD, rowptr, csr, b1, hB);
    // layer 2
    k_gemm_bf16<<<gg, 256, 0, stream>>>(hB, wt2, hA, N_NODES, F1);
    k_attn<<<N_NODES / 4, 256, 0, stream>>>(hA, as2, ad2, alS, alD);
    k_agg <<<N_NODES / 4, 256, 0, stream>>>(hA, alS, alD, rowptr, csr, b2, hB);
    // conv + final linear
    k_conv<<<(N_NODES + 127) / 128, 256, 0, stream>>>(hB, cwt, cb, y);
    k_lin <<<(N_NODES + 255) / 256, 256, 0, stream>>>(y, lw, lb, out);
}

// Round 11
// 483.943 us; speedup vs baseline: 1.6862x; 1.1896x over previous
//
#include <hip/hip_runtime.h>
#include <hip/hip_bf16.h>

#define N_NODES 50000
#define N_EDGES 800000
#define E_TOT   (N_EDGES + N_NODES)   /* 850000: edges + self-loops */
#define IN_CH   128
#define HID     64
#define HEADS   4
#define F1      256                   /* HEADS*HID */
#define OUT_CH  12
#define NEG_SLOPE 0.2f
#define CAP     256                   /* cached edges per node (deg ~Poisson(17); overflow has fallback) */

typedef __attribute__((ext_vector_type(8))) short  bf16x8;
typedef __attribute__((ext_vector_type(4))) float  f32x4;

__device__ __forceinline__ float leaky(float x) { return x > 0.f ? x : NEG_SLOPE * x; }

// f32 -> bf16 round-to-nearest-even
__device__ __forceinline__ unsigned short tob(float f) {
    unsigned u = __float_as_uint(f);
    u += 0x7fffu + ((u >> 16) & 1u);
    return (unsigned short)(u >> 16);
}
__device__ __forceinline__ float fromb(unsigned short s) {
    return __uint_as_float(((unsigned)s) << 16);
}

// ---------------- CSR build ----------------
__global__ void k_zero(int* p, int n) {
    int i = blockIdx.x * blockDim.x + threadIdx.x;
    if (i < n) p[i] = 0;
}

__global__ void k_count(const int* __restrict__ ei, int* __restrict__ counts) {
    int i = blockIdx.x * blockDim.x + threadIdx.x;
    if (i >= E_TOT) return;
    int dst = (i < N_EDGES) ? ei[N_EDGES + i] : (i - N_EDGES);
    atomicAdd(&counts[dst], 1);
}

// single-block exclusive scan, shuffle-based
__global__ __launch_bounds__(1024) void k_scan(const int* __restrict__ counts,
                                               int* __restrict__ rowptr,
                                               int* __restrict__ cursor) {
    __shared__ int wsum[16];
    __shared__ int carrysh;
    const int lane = threadIdx.x & 63, w = threadIdx.x >> 6;
    if (threadIdx.x == 0) carrysh = 0;
    __syncthreads();
    for (int base = 0; base < N_NODES; base += 1024) {
        int i = base + threadIdx.x;
        int v = (i < N_NODES) ? counts[i] : 0;
        int s = v;
        #pragma unroll
        for (int off = 1; off < 64; off <<= 1) {
            int t = __shfl_up(s, off);
            if (lane >= off) s += t;
        }
        if (lane == 63) wsum[w] = s;
        __syncthreads();
        int woff = 0;
        for (int j = 0; j < w; ++j) woff += wsum[j];
        int incl = carrysh + woff + s;
        if (i < N_NODES) { rowptr[i] = incl - v; cursor[i] = incl - v; }
        __syncthreads();
        if (threadIdx.x == 1023) carrysh = incl;
        __syncthreads();
    }
    if (threadIdx.x == 0) rowptr[N_NODES] = carrysh;
}

__global__ void k_fill(const int* __restrict__ ei, int* __restrict__ cursor,
                       int* __restrict__ csr_src) {
    int i = blockIdx.x * blockDim.x + threadIdx.x;
    if (i >= E_TOT) return;
    int src, dst;
    if (i < N_EDGES) { src = ei[i]; dst = ei[N_EDGES + i]; }
    else             { src = dst = i - N_EDGES; }
    int pos = atomicAdd(&cursor[dst], 1);
    csr_src[pos] = src;
}

// ---------------- casts / weight prep ----------------
__global__ void k_cast4(const float* __restrict__ in, unsigned short* __restrict__ out, int n4) {
    int i = blockIdx.x * blockDim.x + threadIdx.x;
    if (i >= n4) return;
    float4 v = *(const float4*)&in[i * 4];
    ushort4 o;
    o.x = tob(v.x); o.y = tob(v.y); o.z = tob(v.z); o.w = tob(v.w);
    *(ushort4*)&out[i * 4] = o;
}

// WT[n*K+k] = bf16(W[k*N+n]); W is K x N row-major
__global__ void k_prep_wt(const float* __restrict__ W, unsigned short* __restrict__ WT,
                          int K, int N) {
    int idx = blockIdx.x * blockDim.x + threadIdx.x;
    if (idx >= K * N) return;
    int n = idx / K, k = idx % K;
    WT[idx] = tob(W[(size_t)k * N + n]);
}

// conv weights CW[o][c][k] (64 x 256 x 3) -> BT[o][kseg*256+c]  (64 x 768)
__global__ void k_prep_cw(const float* __restrict__ CW, unsigned short* __restrict__ BT) {
    int idx = blockIdx.x * blockDim.x + threadIdx.x;
    if (idx >= 64 * 768) return;
    int o = idx / 768, kk = idx % 768;
    int kseg = kk >> 8, c = kk & 255;
    BT[idx] = tob(CW[((size_t)o * 256 + c) * 3 + kseg]);
}

// ---------------- bf16 MFMA GEMM: C[M,F1] = A[M,K] @ BT[F1,K]^T ----------------
// 128x128 tile, BK=32, 4 waves (2x2), each wave 64x64 via 4x4 frags of 16x16x32.
// Staging: 256 threads x 16 shorts = 4096 = full 128x32 tile.
__global__ __launch_bounds__(256) void k_gemm_bf16(const unsigned short* __restrict__ A,
                                                   const unsigned short* __restrict__ BT,
                                                   unsigned short* __restrict__ C,
                                                   int M, int K) {
    __shared__ unsigned short As[128][40];   // 40 = 32 + 8 pad (row stride 80 B)
    __shared__ unsigned short Bs[128][40];
    const int t    = threadIdx.x;
    const int lane = t & 63, wave = t >> 6;
    const int wr = wave >> 1, wc = wave & 1;
    const int row0 = blockIdx.y * 128, col0 = blockIdx.x * 128;
    const int r = t & 127, half = t >> 7;
    const int l15 = lane & 15, kg = lane >> 4;

    f32x4 acc[4][4];
    #pragma unroll
    for (int m = 0; m < 4; ++m)
        #pragma unroll
        for (int n = 0; n < 4; ++n) acc[m][n] = 0.f;

    for (int k0 = 0; k0 < K; k0 += 32) {
        int ar = row0 + r;
        uint4 av0 = make_uint4(0, 0, 0, 0), av1 = make_uint4(0, 0, 0, 0);
        if (ar < M) {
            const unsigned short* ap = &A[(size_t)ar * K + k0 + half * 16];
            av0 = *(const uint4*)ap;
            av1 = *(const uint4*)(ap + 8);
        }
        *(uint4*)&As[r][half * 16]     = av0;
        *(uint4*)&As[r][half * 16 + 8] = av1;
        const unsigned short* bp = &BT[(size_t)(col0 + r) * K + k0 + half * 16];
        uint4 bv0 = *(const uint4*)bp;
        uint4 bv1 = *(const uint4*)(bp + 8);
        *(uint4*)&Bs[r][half * 16]     = bv0;
        *(uint4*)&Bs[r][half * 16 + 8] = bv1;
        __syncthreads();
        bf16x8 af[4], bf[4];
        #pragma unroll
        for (int m = 0; m < 4; ++m) af[m] = *(const bf16x8*)&As[wr * 64 + m * 16 + l15][kg * 8];
        #pragma unroll
        for (int n = 0; n < 4; ++n) bf[n] = *(const bf16x8*)&Bs[wc * 64 + n * 16 + l15][kg * 8];
        #pragma unroll
        for (int m = 0; m < 4; ++m)
            #pragma unroll
            for (int n = 0; n < 4; ++n)
                acc[m][n] = __builtin_amdgcn_mfma_f32_16x16x32_bf16(af[m], bf[n], acc[m][n], 0, 0, 0);
        __syncthreads();
    }
    #pragma unroll
    for (int m = 0; m < 4; ++m) {
        #pragma unroll
        for (int j = 0; j < 4; ++j) {
            int row = row0 + wr * 64 + m * 16 + (lane >> 4) * 4 + j;
            if (row < M) {
                #pragma unroll
                for (int n = 0; n < 4; ++n)
                    C[(size_t)row * F1 + col0 + wc * 64 + n * 16 + l15] = tob(acc[m][n][j]);
            }
        }
    }
}

// ---------------- attention coefficients from bf16 h ----------------
__global__ __launch_bounds__(256) void k_attn(const unsigned short* __restrict__ H,
                                              const float* __restrict__ a_src,
                                              const float* __restrict__ a_dst,
                                              float* __restrict__ oS,
                                              float* __restrict__ oD) {
    int lane = threadIdx.x & 63, wid = threadIdx.x >> 6;
    int node = blockIdx.x * 4 + wid;
    int head = lane >> 4, cc = (lane & 15) * 4;
    ushort4 hv4 = *(const ushort4*)&H[(size_t)node * F1 + lane * 4];
    float h0 = fromb(hv4.x), h1 = fromb(hv4.y), h2 = fromb(hv4.z), h3 = fromb(hv4.w);
    float4 sv = *(const float4*)&a_src[head * HID + cc];
    float4 dv = *(const float4*)&a_dst[head * HID + cc];
    float s = h0 * sv.x + h1 * sv.y + h2 * sv.z + h3 * sv.w;
    float d = h0 * dv.x + h1 * dv.y + h2 * dv.z + h3 * dv.w;
    #pragma unroll
    for (int off = 1; off < 16; off <<= 1) {
        s += __shfl_xor(s, off);
        d += __shfl_xor(d, off);
    }
    if ((lane & 15) == 0) { oS[node * 4 + head] = s; oD[node * 4 + head] = d; }
}

// ---------------- per-destination softmax + aggregate (one wave per node) ----------------
// Phase 1: lane-parallel online softmax (m,s per head).
// Phase 1.5: lane-parallel per-edge weight w = exp(e-m)/s computed ONCE per edge -> LDS.
// Phase 2: serial edge loop, pure gather-FMA (no exp/leaky/aS in the hot loop).
__global__ __launch_bounds__(256) void k_agg(const unsigned short* __restrict__ H,
                                             const float* __restrict__ aS,
                                             const float* __restrict__ aD,
                                             const int* __restrict__ rowptr,
                                             const int* __restrict__ csr,
                                             const float* __restrict__ bias,
                                             unsigned short* __restrict__ O) {
    __shared__ float wlds[4][CAP][4];   // 16 KB/block
    int lane = threadIdx.x & 63, wid = threadIdx.x >> 6;
    int node = blockIdx.x * 4 + wid;
    int beg = rowptr[node], end = rowptr[node + 1];

    float4 adv = *(const float4*)&aD[node * 4];
    float ad[4] = { adv.x, adv.y, adv.z, adv.w };
    float m[4] = { -1e30f, -1e30f, -1e30f, -1e30f };
    float s[4] = { 0.f, 0.f, 0.f, 0.f };

    for (int j = beg + lane; j < end; j += 64) {
        int src = csr[j];
        float4 asv = *(const float4*)&aS[src * 4];
        float as4[4] = { asv.x, asv.y, asv.z, asv.w };
        #pragma unroll
        for (int h = 0; h < 4; ++h) {
            float e  = leaky(as4[h] + ad[h]);
            float mn = fmaxf(m[h], e);
            s[h] = s[h] * __expf(m[h] - mn) + __expf(e - mn);
            m[h] = mn;
        }
    }
    #pragma unroll
    for (int off = 1; off < 64; off <<= 1) {
        #pragma unroll
        for (int h = 0; h < 4; ++h) {
            float mo = __shfl_xor(m[h], off);
            float so = __shfl_xor(s[h], off);
            float mn = fmaxf(m[h], mo);
            s[h] = s[h] * __expf(m[h] - mn) + so * __expf(mo - mn);
            m[h] = mn;
        }
    }
    float inv4[4];
    #pragma unroll
    for (int h = 0; h < 4; ++h) inv4[h] = 1.f / (s[h] + 1e-16f);

    // phase 1.5: per-edge weights into LDS, one lane per edge (all 4 heads at once)
    for (int j = beg + lane, idx = lane; j < end && idx < CAP; j += 64, idx += 64) {
        int src = csr[j];
        float4 asv = *(const float4*)&aS[src * 4];
        float4 w4;
        w4.x = __expf(leaky(asv.x + ad[0]) - m[0]) * inv4[0];
        w4.y = __expf(leaky(asv.y + ad[1]) - m[1]) * inv4[1];
        w4.z = __expf(leaky(asv.z + ad[2]) - m[2]) * inv4[2];
        w4.w = __expf(leaky(asv.w + ad[3]) - m[3]) * inv4[3];
        *(float4*)&wlds[wid][idx][0] = w4;
    }

    int   hl   = lane >> 4;
    float mh   = m[hl];
    float invh = inv4[hl];
    float adh  = ad[hl];
    float a0 = 0.f, a1 = 0.f, a2 = 0.f, a3 = 0.f;
    int deg  = end - beg;
    int degc = deg < CAP ? deg : CAP;
    for (int idx = 0; idx < degc; ++idx) {
        int src = csr[beg + idx];
        float w = wlds[wid][idx][hl];
        ushort4 hv = *(const ushort4*)&H[(size_t)src * F1 + lane * 4];
        a0 += w * fromb(hv.x); a1 += w * fromb(hv.y);
        a2 += w * fromb(hv.z); a3 += w * fromb(hv.w);
    }
    for (int idx = CAP; idx < deg; ++idx) {   // overflow fallback (virtually never taken)
        int src = csr[beg + idx];
        float e = leaky(aS[src * 4 + hl] + adh);
        float w = __expf(e - mh) * invh;
        ushort4 hv = *(const ushort4*)&H[(size_t)src * F1 + lane * 4];
        a0 += w * fromb(hv.x); a1 += w * fromb(hv.y);
        a2 += w * fromb(hv.z); a3 += w * fromb(hv.w);
    }
    float4 bv = *(const float4*)&bias[lane * 4];
    ushort4 o;
    o.x = tob(fmaxf(a0 + bv.x, 0.f));
    o.y = tob(fmaxf(a1 + bv.y, 0.f));
    o.z = tob(fmaxf(a2 + bv.z, 0.f));
    o.w = tob(fmaxf(a3 + bv.w, 0.f));
    *(ushort4*)&O[(size_t)node * F1 + lane * 4] = o;
}

// ---------------- Conv1d as MFMA GEMM: Y[M,64] = A[M,768] @ BcT[64,768]^T ----------------
// A[n, kseg*256+c] = H[n+kseg-1, c] (zero-padded rows)
__global__ __launch_bounds__(256) void k_conv(const unsigned short* __restrict__ H,
                                              const unsigned short* __restrict__ BcT,
                                              const float* __restrict__ CB,
                                              float* __restrict__ Y) {
    __shared__ unsigned short As[128][40];
    __shared__ unsigned short Bs[64][40];
    const int t    = threadIdx.x;
    const int lane = t & 63, wave = t >> 6;     // wave = wr (4x1), wc = 0
    const int row0 = blockIdx.x * 128;
    const int r = t & 127, half = t >> 7;
    const int l15 = lane & 15, kg = lane >> 4;

    f32x4 acc[2][4];
    #pragma unroll
    for (int m = 0; m < 2; ++m)
        #pragma unroll
        for (int n = 0; n < 4; ++n) acc[m][n] = 0.f;

    for (int k0 = 0; k0 < 768; k0 += 32) {
        int kseg = k0 >> 8;
        int cbase = (k0 & 255) + half * 16;
        int gr = row0 + r + kseg - 1;
        uint4 av0 = make_uint4(0, 0, 0, 0), av1 = make_uint4(0, 0, 0, 0);
        if (gr >= 0 && gr < N_NODES) {
            const unsigned short* hp = &H[(size_t)gr * F1 + cbase];
            av0 = *(const uint4*)hp;
            av1 = *(const uint4*)(hp + 8);
        }
        *(uint4*)&As[r][half * 16]     = av0;
        *(uint4*)&As[r][half * 16 + 8] = av1;
        if (t < 128) {
            int br = t & 63, bh = t >> 6;
            const unsigned short* bp = &BcT[(size_t)br * 768 + k0 + bh * 16];
            uint4 bv0 = *(const uint4*)bp;
            uint4 bv1 = *(const uint4*)(bp + 8);
            *(uint4*)&Bs[br][bh * 16]     = bv0;
            *(uint4*)&Bs[br][bh * 16 + 8] = bv1;
        }
        __syncthreads();
        bf16x8 af[2], bf[4];
        #pragma unroll
        for (int m = 0; m < 2; ++m) af[m] = *(const bf16x8*)&As[wave * 32 + m * 16 + l15][kg * 8];
        #pragma unroll
        for (int n = 0; n < 4; ++n) bf[n] = *(const bf16x8*)&Bs[n * 16 + l15][kg * 8];
        #pragma unroll
        for (int m = 0; m < 2; ++m)
            #pragma unroll
            for (int n = 0; n < 4; ++n)
                acc[m][n] = __builtin_amdgcn_mfma_f32_16x16x32_bf16(af[m], bf[n], acc[m][n], 0, 0, 0);
        __syncthreads();
    }
    #pragma unroll
    for (int m = 0; m < 2; ++m) {
        #pragma unroll
        for (int j = 0; j < 4; ++j) {
            int row = row0 + wave * 32 + m * 16 + (lane >> 4) * 4 + j;
            if (row < N_NODES) {
                #pragma unroll
                for (int n = 0; n < 4; ++n) {
                    int col = n * 16 + l15;
                    Y[(size_t)row * HID + col] = fmaxf(acc[m][n][j] + CB[col], 0.f);
                }
            }
        }
    }
}

// ---------------- final linear ----------------
__global__ __launch_bounds__(256) void k_lin(const float* __restrict__ Y,
                                             const float* __restrict__ LW,
                                             const float* __restrict__ LB,
                                             float* __restrict__ OUT) {
    __shared__ float w[64][12];
    __shared__ float b[12];
    for (int i = threadIdx.x; i < 64 * 12; i += 256) w[i / 12][i % 12] = LW[i];
    if (threadIdx.x < 12) b[threadIdx.x] = LB[threadIdx.x];
    __syncthreads();
    int n = blockIdx.x * 256 + threadIdx.x;
    if (n >= N_NODES) return;
    float acc[12];
    #pragma unroll
    for (int o = 0; o < 12; ++o) acc[o] = b[o];
    for (int c = 0; c < 64; c += 4) {
        float4 yv = *(const float4*)&Y[(size_t)n * HID + c];
        #pragma unroll
        for (int o = 0; o < 12; ++o)
            acc[o] += yv.x * w[c][o] + yv.y * w[c + 1][o]
                    + yv.z * w[c + 2][o] + yv.w * w[c + 3][o];
    }
    #pragma unroll
    for (int o = 0; o < 12; ++o) OUT[(size_t)n * OUT_CH + o] = acc[o];
}

extern "C" void kernel_launch(void* const* d_in, const int* in_sizes, int n_in,
                              void* d_out, int out_size, void* d_ws, size_t ws_size,
                              hipStream_t stream) {
    const float* x   = (const float*)d_in[0];
    const int*   ei  = (const int*)d_in[1];
    const float* W1  = (const float*)d_in[2];
    const float* as1 = (const float*)d_in[3];
    const float* ad1 = (const float*)d_in[4];
    const float* b1  = (const float*)d_in[5];
    const float* W2  = (const float*)d_in[6];
    const float* as2 = (const float*)d_in[7];
    const float* ad2 = (const float*)d_in[8];
    const float* b2  = (const float*)d_in[9];
    const float* cw  = (const float*)d_in[10];
    const float* cb  = (const float*)d_in[11];
    const float* lw  = (const float*)d_in[12];
    const float* lb  = (const float*)d_in[13];
    float* out = (float*)d_out;

    char* ws = (char*)d_ws;
    size_t off = 0;
    auto alloc = [&](size_t bytes) -> void* {
        off = (off + 255) & ~(size_t)255;
        void* p = ws + off;
        off += bytes;
        return p;
    };
    unsigned short* hA  = (unsigned short*)alloc((size_t)N_NODES * F1 * 2);  // gemm out (h)
    unsigned short* hB  = (unsigned short*)alloc((size_t)N_NODES * F1 * 2);  // agg out
    unsigned short* xb  = (unsigned short*)alloc((size_t)N_NODES * IN_CH * 2);
    unsigned short* wt1 = (unsigned short*)alloc((size_t)F1 * IN_CH * 2);
    unsigned short* wt2 = (unsigned short*)alloc((size_t)F1 * F1 * 2);
    unsigned short* cwt = (unsigned short*)alloc((size_t)HID * 768 * 2);
    float* alS    = (float*)alloc((size_t)N_NODES * 4 * 4);
    float* alD    = (float*)alloc((size_t)N_NODES * 4 * 4);
    int*   counts = (int*)  alloc((size_t)N_NODES * 4);
    int*   rowptr = (int*)  alloc((size_t)(N_NODES + 1) * 4);
    int*   cursor = (int*)  alloc((size_t)N_NODES * 4);
    int*   csr    = (int*)  alloc((size_t)E_TOT * 4);
    float* y      = (float*)alloc((size_t)N_NODES * HID * 4);

    // CSR build
    k_zero <<<(N_NODES + 255) / 256, 256, 0, stream>>>(counts, N_NODES);
    k_count<<<(E_TOT + 255) / 256, 256, 0, stream>>>(ei, counts);
    k_scan <<<1, 1024, 0, stream>>>(counts, rowptr, cursor);
    k_fill <<<(E_TOT + 255) / 256, 256, 0, stream>>>(ei, cursor, csr);

    // casts / weight prep
    k_cast4 <<<(N_NODES * IN_CH / 4 + 255) / 256, 256, 0, stream>>>(x, xb, N_NODES * IN_CH / 4);
    k_prep_wt<<<(IN_CH * F1 + 255) / 256, 256, 0, stream>>>(W1, wt1, IN_CH, F1);
    k_prep_wt<<<(F1 * F1 + 255) / 256, 256, 0, stream>>>(W2, wt2, F1, F1);
    k_prep_cw<<<(HID * 768 + 255) / 256, 256, 0, stream>>>(cw, cwt);

    dim3 gg(F1 / 128, (N_NODES + 127) / 128);
    // layer 1
    k_gemm_bf16<<<gg, 256, 0, stream>>>(xb, wt1, hA, N_NODES, IN_CH);
    k_attn<<<N_NODES / 4, 256, 0, stream>>>(hA, as1, ad1, alS, alD);
    k_agg <<<N_NODES / 4, 256, 0, stream>>>(hA, alS, alD, rowptr, csr, b1, hB);
    // layer 2
    k_gemm_bf16<<<gg, 256, 0, stream>>>(hB, wt2, hA, N_NODES, F1);
    k_attn<<<N_NODES / 4, 256, 0, stream>>>(hA, as2, ad2, alS, alD);
    k_agg <<<N_NODES / 4, 256, 0, stream>>>(hA, alS, alD, rowptr, csr, b2, hB);
    // conv + final linear
    k_conv<<<(N_NODES + 127) / 128, 256, 0, stream>>>(hB, cwt, cb, y);
    k_lin <<<(N_NODES + 255) / 256, 256, 0, stream>>>(y, lw, lb, out);
}

// Round 12
// 468.896 us; speedup vs baseline: 1.7403x; 1.0321x over previous
//
#include <hip/hip_runtime.h>
#include <hip/hip_bf16.h>

#define N_NODES 50000
#define N_EDGES 800000
#define E_TOT   (N_EDGES + N_NODES)   /* 850000: edges + self-loops */
#define IN_CH   128
#define HID     64
#define HEADS   4
#define F1      256                   /* HEADS*HID */
#define OUT_CH  12
#define NEG_SLOPE 0.2f
#define CAP     256                   /* cached edges per node (deg ~Poisson(17); overflow has fallback) */

typedef __attribute__((ext_vector_type(8))) short  bf16x8;
typedef __attribute__((ext_vector_type(4))) float  f32x4;

__device__ __forceinline__ float leaky(float x) { return x > 0.f ? x : NEG_SLOPE * x; }

// f32 -> bf16 round-to-nearest-even
__device__ __forceinline__ unsigned short tob(float f) {
    unsigned u = __float_as_uint(f);
    u += 0x7fffu + ((u >> 16) & 1u);
    return (unsigned short)(u >> 16);
}
__device__ __forceinline__ float fromb(unsigned short s) {
    return __uint_as_float(((unsigned)s) << 16);
}

// async global->LDS, 16 B per lane; LDS dest = wave-uniform base + lane*16
typedef __attribute__((address_space(3))) unsigned int        lds_u32;
typedef const __attribute__((address_space(1))) unsigned int  glb_u32;
__device__ __forceinline__ void gload16(const void* g, void* l) {
    __builtin_amdgcn_global_load_lds((glb_u32*)g, (lds_u32*)l, 16, 0, 0);
}

// ---------------- CSR build ----------------
__global__ void k_zero(int* p, int n) {
    int i = blockIdx.x * blockDim.x + threadIdx.x;
    if (i < n) p[i] = 0;
}

// zero the two guard rows around hB (for conv's n-1 / n+1 reads)
__global__ void k_guard(unsigned int* front, unsigned int* back) {
    int i = threadIdx.x;
    if (i < 128) front[i] = 0;
    else         back[i - 128] = 0;
}

__global__ void k_count(const int* __restrict__ ei, int* __restrict__ counts) {
    int i = blockIdx.x * blockDim.x + threadIdx.x;
    if (i >= E_TOT) return;
    int dst = (i < N_EDGES) ? ei[N_EDGES + i] : (i - N_EDGES);
    atomicAdd(&counts[dst], 1);
}

// single-block exclusive scan, shuffle-based
__global__ __launch_bounds__(1024) void k_scan(const int* __restrict__ counts,
                                               int* __restrict__ rowptr,
                                               int* __restrict__ cursor) {
    __shared__ int wsum[16];
    __shared__ int carrysh;
    const int lane = threadIdx.x & 63, w = threadIdx.x >> 6;
    if (threadIdx.x == 0) carrysh = 0;
    __syncthreads();
    for (int base = 0; base < N_NODES; base += 1024) {
        int i = base + threadIdx.x;
        int v = (i < N_NODES) ? counts[i] : 0;
        int s = v;
        #pragma unroll
        for (int off = 1; off < 64; off <<= 1) {
            int t = __shfl_up(s, off);
            if (lane >= off) s += t;
        }
        if (lane == 63) wsum[w] = s;
        __syncthreads();
        int woff = 0;
        for (int j = 0; j < w; ++j) woff += wsum[j];
        int incl = carrysh + woff + s;
        if (i < N_NODES) { rowptr[i] = incl - v; cursor[i] = incl - v; }
        __syncthreads();
        if (threadIdx.x == 1023) carrysh = incl;
        __syncthreads();
    }
    if (threadIdx.x == 0) rowptr[N_NODES] = carrysh;
}

__global__ void k_fill(const int* __restrict__ ei, int* __restrict__ cursor,
                       int* __restrict__ csr_src) {
    int i = blockIdx.x * blockDim.x + threadIdx.x;
    if (i >= E_TOT) return;
    int src, dst;
    if (i < N_EDGES) { src = ei[i]; dst = ei[N_EDGES + i]; }
    else             { src = dst = i - N_EDGES; }
    int pos = atomicAdd(&cursor[dst], 1);
    csr_src[pos] = src;
}

// ---------------- casts / weight prep ----------------
__global__ void k_cast4(const float* __restrict__ in, unsigned short* __restrict__ out, int n4) {
    int i = blockIdx.x * blockDim.x + threadIdx.x;
    if (i >= n4) return;
    float4 v = *(const float4*)&in[i * 4];
    ushort4 o;
    o.x = tob(v.x); o.y = tob(v.y); o.z = tob(v.z); o.w = tob(v.w);
    *(ushort4*)&out[i * 4] = o;
}

// WT[n*K+k] = bf16(W[k*N+n]); W is K x N row-major
__global__ void k_prep_wt(const float* __restrict__ W, unsigned short* __restrict__ WT,
                          int K, int N) {
    int idx = blockIdx.x * blockDim.x + threadIdx.x;
    if (idx >= K * N) return;
    int n = idx / K, k = idx % K;
    WT[idx] = tob(W[(size_t)k * N + n]);
}

// conv weights CW[o][c][k] (64 x 256 x 3) -> BT[o][kseg*256+c]  (64 x 768)
__global__ void k_prep_cw(const float* __restrict__ CW, unsigned short* __restrict__ BT) {
    int idx = blockIdx.x * blockDim.x + threadIdx.x;
    if (idx >= 64 * 768) return;
    int o = idx / 768, kk = idx % 768;
    int kseg = kk >> 8, c = kk & 255;
    BT[idx] = tob(CW[((size_t)o * 256 + c) * 3 + kseg]);
}

// ---------------- bf16 MFMA GEMM: C[M,F1] = A[M,K] @ BT[F1,K]^T ----------------
// 128x128 tile, BK=32, 4 waves (2x2), global_load_lds width-16 staging, linear LDS.
__global__ __launch_bounds__(256) void k_gemm_bf16(const unsigned short* __restrict__ A,
                                                   const unsigned short* __restrict__ BT,
                                                   unsigned short* __restrict__ C,
                                                   int M, int K) {
    __shared__ unsigned short As[128][32];   // linear (gload_lds requirement)
    __shared__ unsigned short Bs[128][32];
    const int t    = threadIdx.x;
    const int lane = t & 63, wave = t >> 6;
    const int wr = wave >> 1, wc = wave & 1;
    const int row0 = blockIdx.y * 128, col0 = blockIdx.x * 128;
    const int l15 = lane & 15, kg = lane >> 4;

    // gload mapping: issue i covers LDS rows wave*16 + (lane>>2) + i*64, 16B chunk (lane&3)
    const int srow = (wave << 4) + (lane >> 2);
    const int sseg = (lane & 3) * 8;             // shorts
    int ar0 = row0 + srow;      if (ar0 >= M) ar0 = M - 1;   // clamp: OOB rows discarded at C-write
    int ar1 = row0 + srow + 64; if (ar1 >= M) ar1 = M - 1;
    const int br0 = col0 + srow, br1 = col0 + srow + 64;     // always < F1
    unsigned short* ldsA = &As[0][0];
    unsigned short* ldsB = &Bs[0][0];
    const int lofs0 = wave * 512, lofs1 = 2048 + wave * 512; // shorts (1024 B / wave issue)

    f32x4 acc[4][4];
    #pragma unroll
    for (int m = 0; m < 4; ++m)
        #pragma unroll
        for (int n = 0; n < 4; ++n) acc[m][n] = 0.f;

    for (int k0 = 0; k0 < K; k0 += 32) {
        gload16(&A [(size_t)ar0 * K + k0 + sseg], ldsA + lofs0);
        gload16(&A [(size_t)ar1 * K + k0 + sseg], ldsA + lofs1);
        gload16(&BT[(size_t)br0 * K + k0 + sseg], ldsB + lofs0);
        gload16(&BT[(size_t)br1 * K + k0 + sseg], ldsB + lofs1);
        __syncthreads();
        bf16x8 af[4], bf[4];
        #pragma unroll
        for (int m = 0; m < 4; ++m) af[m] = *(const bf16x8*)&As[wr * 64 + m * 16 + l15][kg * 8];
        #pragma unroll
        for (int n = 0; n < 4; ++n) bf[n] = *(const bf16x8*)&Bs[wc * 64 + n * 16 + l15][kg * 8];
        #pragma unroll
        for (int m = 0; m < 4; ++m)
            #pragma unroll
            for (int n = 0; n < 4; ++n)
                acc[m][n] = __builtin_amdgcn_mfma_f32_16x16x32_bf16(af[m], bf[n], acc[m][n], 0, 0, 0);
        __syncthreads();
    }
    #pragma unroll
    for (int m = 0; m < 4; ++m) {
        #pragma unroll
        for (int j = 0; j < 4; ++j) {
            int row = row0 + wr * 64 + m * 16 + (lane >> 4) * 4 + j;
            if (row < M) {
                #pragma unroll
                for (int n = 0; n < 4; ++n)
                    C[(size_t)row * F1 + col0 + wc * 64 + n * 16 + l15] = tob(acc[m][n][j]);
            }
        }
    }
}

// ---------------- attention coefficients from bf16 h ----------------
__global__ __launch_bounds__(256) void k_attn(const unsigned short* __restrict__ H,
                                              const float* __restrict__ a_src,
                                              const float* __restrict__ a_dst,
                                              float* __restrict__ oS,
                                              float* __restrict__ oD) {
    int lane = threadIdx.x & 63, wid = threadIdx.x >> 6;
    int node = blockIdx.x * 4 + wid;
    int head = lane >> 4, cc = (lane & 15) * 4;
    ushort4 hv4 = *(const ushort4*)&H[(size_t)node * F1 + lane * 4];
    float h0 = fromb(hv4.x), h1 = fromb(hv4.y), h2 = fromb(hv4.z), h3 = fromb(hv4.w);
    float4 sv = *(const float4*)&a_src[head * HID + cc];
    float4 dv = *(const float4*)&a_dst[head * HID + cc];
    float s = h0 * sv.x + h1 * sv.y + h2 * sv.z + h3 * sv.w;
    float d = h0 * dv.x + h1 * dv.y + h2 * dv.z + h3 * dv.w;
    #pragma unroll
    for (int off = 1; off < 16; off <<= 1) {
        s += __shfl_xor(s, off);
        d += __shfl_xor(d, off);
    }
    if ((lane & 15) == 0) { oS[node * 4 + head] = s; oD[node * 4 + head] = d; }
}

// ---------------- per-destination softmax + aggregate (one wave per node) ----------------
// Two-pass softmax: phase1 e->LDS + max-track; max-reduce; phase1.5 w=exp(e-M), s accum;
// sum-reduce; phase2 unnormalized gather-FMA; epilogue multiplies by 1/s.
__global__ __launch_bounds__(256) void k_agg(const unsigned short* __restrict__ H,
                                             const float* __restrict__ aS,
                                             const float* __restrict__ aD,
                                             const int* __restrict__ rowptr,
                                             const int* __restrict__ csr,
                                             const float* __restrict__ bias,
                                             unsigned short* __restrict__ O) {
    __shared__ float wlds[4][CAP][4];   // 16 KB/block
    int lane = threadIdx.x & 63, wid = threadIdx.x >> 6;
    int node = blockIdx.x * 4 + wid;
    int beg = rowptr[node], end = rowptr[node + 1];
    int deg = end - beg;

    float4 adv = *(const float4*)&aD[node * 4];
    float ad[4] = { adv.x, adv.y, adv.z, adv.w };
    float m[4] = { -1e30f, -1e30f, -1e30f, -1e30f };

    // phase 1: e -> LDS, track max only (no exp)
    for (int j = beg + lane, idx = lane; j < end; j += 64, idx += 64) {
        int src = csr[j];
        float4 asv = *(const float4*)&aS[src * 4];
        float4 e4;
        e4.x = leaky(asv.x + ad[0]);
        e4.y = leaky(asv.y + ad[1]);
        e4.z = leaky(asv.z + ad[2]);
        e4.w = leaky(asv.w + ad[3]);
        m[0] = fmaxf(m[0], e4.x); m[1] = fmaxf(m[1], e4.y);
        m[2] = fmaxf(m[2], e4.z); m[3] = fmaxf(m[3], e4.w);
        if (idx < CAP) *(float4*)&wlds[wid][idx][0] = e4;
    }
    #pragma unroll
    for (int off = 1; off < 64; off <<= 1) {
        #pragma unroll
        for (int h = 0; h < 4; ++h) m[h] = fmaxf(m[h], __shfl_xor(m[h], off));
    }

    // phase 1.5: w = exp(e - M) in place, accumulate s
    float s[4] = { 0.f, 0.f, 0.f, 0.f };
    int degc = deg < CAP ? deg : CAP;
    for (int idx = lane; idx < degc; idx += 64) {
        float4 e4 = *(float4*)&wlds[wid][idx][0];
        float4 w4;
        w4.x = __expf(e4.x - m[0]); w4.y = __expf(e4.y - m[1]);
        w4.z = __expf(e4.z - m[2]); w4.w = __expf(e4.w - m[3]);
        s[0] += w4.x; s[1] += w4.y; s[2] += w4.z; s[3] += w4.w;
        *(float4*)&wlds[wid][idx][0] = w4;
    }
    for (int j = beg + CAP + lane; j < end; j += 64) {   // overflow: count into s
        int src = csr[j];
        float4 asv = *(const float4*)&aS[src * 4];
        s[0] += __expf(leaky(asv.x + ad[0]) - m[0]);
        s[1] += __expf(leaky(asv.y + ad[1]) - m[1]);
        s[2] += __expf(leaky(asv.z + ad[2]) - m[2]);
        s[3] += __expf(leaky(asv.w + ad[3]) - m[3]);
    }
    #pragma unroll
    for (int off = 1; off < 64; off <<= 1) {
        #pragma unroll
        for (int h = 0; h < 4; ++h) s[h] += __shfl_xor(s[h], off);
    }

    int   hl   = lane >> 4;
    float invh = 1.f / (s[hl] + 1e-16f);
    float mh   = m[hl];
    float adh  = ad[hl];
    float a0 = 0.f, a1 = 0.f, a2 = 0.f, a3 = 0.f;
    for (int idx = 0; idx < degc; ++idx) {
        int src = csr[beg + idx];
        float w = wlds[wid][idx][hl];
        ushort4 hv = *(const ushort4*)&H[(size_t)src * F1 + lane * 4];
        a0 += w * fromb(hv.x); a1 += w * fromb(hv.y);
        a2 += w * fromb(hv.z); a3 += w * fromb(hv.w);
    }
    for (int idx = CAP; idx < deg; ++idx) {   // overflow fallback (virtually never taken)
        int src = csr[beg + idx];
        float w = __expf(leaky(aS[src * 4 + hl] + adh) - mh);
        ushort4 hv = *(const ushort4*)&H[(size_t)src * F1 + lane * 4];
        a0 += w * fromb(hv.x); a1 += w * fromb(hv.y);
        a2 += w * fromb(hv.z); a3 += w * fromb(hv.w);
    }
    float4 bv = *(const float4*)&bias[lane * 4];
    ushort4 o;
    o.x = tob(fmaxf(a0 * invh + bv.x, 0.f));
    o.y = tob(fmaxf(a1 * invh + bv.y, 0.f));
    o.z = tob(fmaxf(a2 * invh + bv.z, 0.f));
    o.w = tob(fmaxf(a3 * invh + bv.w, 0.f));
    *(ushort4*)&O[(size_t)node * F1 + lane * 4] = o;
}

// ---------------- Conv1d as MFMA GEMM: Y[M,64] = A[M,768] @ BcT[64,768]^T ----------------
// A[n, kseg*256+c] = H[n+kseg-1, c]; H has zeroed guard rows at -1 and N (hB padding).
__global__ __launch_bounds__(256) void k_conv(const unsigned short* __restrict__ H,
                                              const unsigned short* __restrict__ BcT,
                                              const float* __restrict__ CB,
                                              float* __restrict__ Y) {
    __shared__ unsigned short As[128][32];
    __shared__ unsigned short Bs[64][32];
    const int t    = threadIdx.x;
    const int lane = t & 63, wave = t >> 6;     // 4 waves stacked on M
    const int row0 = blockIdx.x * 128;
    const int l15 = lane & 15, kg = lane >> 4;

    const int srow = (wave << 4) + (lane >> 2);
    const int sseg = (lane & 3) * 8;
    unsigned short* ldsA = &As[0][0];
    unsigned short* ldsB = &Bs[0][0];
    const int lofs0 = wave * 512, lofs1 = 2048 + wave * 512;

    f32x4 acc[2][4];
    #pragma unroll
    for (int m = 0; m < 2; ++m)
        #pragma unroll
        for (int n = 0; n < 4; ++n) acc[m][n] = 0.f;

    for (int k0 = 0; k0 < 768; k0 += 32) {
        int kseg  = k0 >> 8;
        int cbase = (k0 & 255) + sseg;
        int gr0 = row0 + srow + kseg - 1;      // >= -1 (guard row)
        int gr1 = gr0 + 64;
        if (gr1 > N_NODES) gr1 = N_NODES;      // clamp to back guard (zeros; rows discarded anyway)
        gload16(H + (ptrdiff_t)gr0 * F1 + cbase, ldsA + lofs0);
        gload16(H + (ptrdiff_t)gr1 * F1 + cbase, ldsA + lofs1);
        { // B tile: 64x32, one issue per wave
            int brow = srow;                   // < 64
            gload16(&BcT[(size_t)brow * 768 + k0 + sseg], ldsB + lofs0);
        }
        __syncthreads();
        bf16x8 af[2], bf[4];
        #pragma unroll
        for (int m = 0; m < 2; ++m) af[m] = *(const bf16x8*)&As[wave * 32 + m * 16 + l15][kg * 8];
        #pragma unroll
        for (int n = 0; n < 4; ++n) bf[n] = *(const bf16x8*)&Bs[n * 16 + l15][kg * 8];
        #pragma unroll
        for (int m = 0; m < 2; ++m)
            #pragma unroll
            for (int n = 0; n < 4; ++n)
                acc[m][n] = __builtin_amdgcn_mfma_f32_16x16x32_bf16(af[m], bf[n], acc[m][n], 0, 0, 0);
        __syncthreads();
    }
    #pragma unroll
    for (int m = 0; m < 2; ++m) {
        #pragma unroll
        for (int j = 0; j < 4; ++j) {
            int row = row0 + wave * 32 + m * 16 + (lane >> 4) * 4 + j;
            if (row < N_NODES) {
                #pragma unroll
                for (int n = 0; n < 4; ++n) {
                    int col = n * 16 + l15;
                    Y[(size_t)row * HID + col] = fmaxf(acc[m][n][j] + CB[col], 0.f);
                }
            }
        }
    }
}

// ---------------- final linear ----------------
__global__ __launch_bounds__(256) void k_lin(const float* __restrict__ Y,
                                             const float* __restrict__ LW,
                                             const float* __restrict__ LB,
                                             float* __restrict__ OUT) {
    __shared__ float w[64][12];
    __shared__ float b[12];
    for (int i = threadIdx.x; i < 64 * 12; i += 256) w[i / 12][i % 12] = LW[i];
    if (threadIdx.x < 12) b[threadIdx.x] = LB[threadIdx.x];
    __syncthreads();
    int n = blockIdx.x * 256 + threadIdx.x;
    if (n >= N_NODES) return;
    float acc[12];
    #pragma unroll
    for (int o = 0; o < 12; ++o) acc[o] = b[o];
    for (int c = 0; c < 64; c += 4) {
        float4 yv = *(const float4*)&Y[(size_t)n * HID + c];
        #pragma unroll
        for (int o = 0; o < 12; ++o)
            acc[o] += yv.x * w[c][o] + yv.y * w[c + 1][o]
                    + yv.z * w[c + 2][o] + yv.w * w[c + 3][o];
    }
    #pragma unroll
    for (int o = 0; o < 12; ++o) OUT[(size_t)n * OUT_CH + o] = acc[o];
}

extern "C" void kernel_launch(void* const* d_in, const int* in_sizes, int n_in,
                              void* d_out, int out_size, void* d_ws, size_t ws_size,
                              hipStream_t stream) {
    const float* x   = (const float*)d_in[0];
    const int*   ei  = (const int*)d_in[1];
    const float* W1  = (const float*)d_in[2];
    const float* as1 = (const float*)d_in[3];
    const float* ad1 = (const float*)d_in[4];
    const float* b1  = (const float*)d_in[5];
    const float* W2  = (const float*)d_in[6];
    const float* as2 = (const float*)d_in[7];
    const float* ad2 = (const float*)d_in[8];
    const float* b2  = (const float*)d_in[9];
    const float* cw  = (const float*)d_in[10];
    const float* cb  = (const float*)d_in[11];
    const float* lw  = (const float*)d_in[12];
    const float* lb  = (const float*)d_in[13];
    float* out = (float*)d_out;

    char* ws = (char*)d_ws;
    size_t off = 0;
    auto alloc = [&](size_t bytes) -> void* {
        off = (off + 255) & ~(size_t)255;
        void* p = ws + off;
        off += bytes;
        return p;
    };
    unsigned short* hA  = (unsigned short*)alloc((size_t)N_NODES * F1 * 2);        // gemm out (h)
    unsigned short* hBg = (unsigned short*)alloc((size_t)(N_NODES + 2) * F1 * 2);  // agg out + guards
    unsigned short* hB  = hBg + F1;                                                // row 0 of real data
    unsigned short* xb  = (unsigned short*)alloc((size_t)N_NODES * IN_CH * 2);
    unsigned short* wt1 = (unsigned short*)alloc((size_t)F1 * IN_CH * 2);
    unsigned short* wt2 = (unsigned short*)alloc((size_t)F1 * F1 * 2);
    unsigned short* cwt = (unsigned short*)alloc((size_t)HID * 768 * 2);
    float* alS    = (float*)alloc((size_t)N_NODES * 4 * 4);
    float* alD    = (float*)alloc((size_t)N_NODES * 4 * 4);
    int*   counts = (int*)  alloc((size_t)N_NODES * 4);
    int*   rowptr = (int*)  alloc((size_t)(N_NODES + 1) * 4);
    int*   cursor = (int*)  alloc((size_t)N_NODES * 4);
    int*   csr    = (int*)  alloc((size_t)E_TOT * 4);
    float* y      = (float*)alloc((size_t)N_NODES * HID * 4);

    // CSR build + guard zeroing
    k_zero <<<(N_NODES + 255) / 256, 256, 0, stream>>>(counts, N_NODES);
    k_guard<<<1, 256, 0, stream>>>((unsigned int*)hBg,
                                   (unsigned int*)(hBg + (size_t)(N_NODES + 1) * F1));
    k_count<<<(E_TOT + 255) / 256, 256, 0, stream>>>(ei, counts);
    k_scan <<<1, 1024, 0, stream>>>(counts, rowptr, cursor);
    k_fill <<<(E_TOT + 255) / 256, 256, 0, stream>>>(ei, cursor, csr);

    // casts / weight prep
    k_cast4 <<<(N_NODES * IN_CH / 4 + 255) / 256, 256, 0, stream>>>(x, xb, N_NODES * IN_CH / 4);
    k_prep_wt<<<(IN_CH * F1 + 255) / 256, 256, 0, stream>>>(W1, wt1, IN_CH, F1);
    k_prep_wt<<<(F1 * F1 + 255) / 256, 256, 0, stream>>>(W2, wt2, F1, F1);
    k_prep_cw<<<(HID * 768 + 255) / 256, 256, 0, stream>>>(cw, cwt);

    dim3 gg(F1 / 128, (N_NODES + 127) / 128);
    // layer 1
    k_gemm_bf16<<<gg, 256, 0, stream>>>(xb, wt1, hA, N_NODES, IN_CH);
    k_attn<<<N_NODES / 4, 256, 0, stream>>>(hA, as1, ad1, alS, alD);
    k_agg <<<N_NODES / 4, 256, 0, stream>>>(hA, alS, alD, rowptr, csr, b1, hB);
    // layer 2
    k_gemm_bf16<<<gg, 256, 0, stream>>>(hB, wt2, hA, N_NODES, F1);
    k_attn<<<N_NODES / 4, 256, 0, stream>>>(hA, as2, ad2, alS, alD);
    k_agg <<<N_NODES / 4, 256, 0, stream>>>(hA, alS, alD, rowptr, csr, b2, hB);
    // conv + final linear
    k_conv<<<(N_NODES + 127) / 128, 256, 0, stream>>>(hB, cwt, cb, y);
    k_lin <<<(N_NODES + 255) / 256, 256, 0, stream>>>(y, lw, lb, out);
}